// Round 4
// baseline (97.812 us; speedup 1.0000x reference)
//
#include <hip/hip_runtime.h>
#include <hip/hip_bf16.h>

// KPConv collapses to: out[c,:] = sum_m s[c,m] * (x[src(c,m),:] @ W[m])
// with s[c,m] = sum of w over neighbors whose argmin kernel point == m.
//
// kprep (1296 indep blocks):
//   [0,512)    s_g[m][c] table: exact-rounding argmin + influence weights
//   [512,528)  W fp32 [16][64][128] -> Wb bf16 [16][128][64] (LDS transpose)
//   [528,1040) x fp32 -> xb bf16
//   [1040,1296) zero d_out (harness poisons it; kmain accumulates atomically)
// kmain: pure GEMM, no barriers, no LDS. K-split x2 (m 0..7 / 8..15) via
//   fp32 atomicAdd -> 1024 blocks x 4 waves = 4 waves/SIMD. Fragments loaded
//   directly from global in MFMA layout; all 8 src indices fetched up front;
//   A 2-ahead ring, B/SV 1-ahead; s applied post-MFMA in fp32.

#define KPE 0.6666667f  // float(1.0/1.5), matches numpy f32 promotion

typedef short short8 __attribute__((ext_vector_type(8)));
typedef float floatx4 __attribute__((ext_vector_type(4)));

__device__ inline unsigned short f2bf(float f) {
    __hip_bfloat16 h = __float2bfloat16(f);
    return __builtin_bit_cast(unsigned short, h);
}

__global__ __launch_bounds__(256) void kprep(
    const float* __restrict__ Wf, const float* __restrict__ x,
    const float* __restrict__ pos, const int* __restrict__ esrc,
    const int* __restrict__ etgt, const float* __restrict__ kpts,
    unsigned short* __restrict__ Wb, unsigned short* __restrict__ xb,
    float* __restrict__ s_g, float* __restrict__ out)
{
    const int t = threadIdx.x;
    const int b = blockIdx.x;
    if (b < 512) {
        // ---- s[c,m] for 16 centers (256 edges) ----
        __shared__ float kps[48];
        __shared__ float wv[16 * 17];
        __shared__ int   nnv[16 * 17];
        if (t < 48) kps[t] = kpts[t];
        const int e   = b * 256 + t;
        const int src = esrc[e];
        const int tgt = etgt[e];
        float rx = __fsub_rn(pos[tgt * 3 + 0], pos[src * 3 + 0]);
        float ry = __fsub_rn(pos[tgt * 3 + 1], pos[src * 3 + 1]);
        float rz = __fsub_rn(pos[tgt * 3 + 2], pos[src * 3 + 2]);
        __syncthreads();                       // kps visible
        float best = 1e30f; int nn = 0;
#pragma unroll
        for (int k = 0; k < 16; ++k) {
            float dx = __fsub_rn(rx, kps[k * 3 + 0]);
            float dy = __fsub_rn(ry, kps[k * 3 + 1]);
            float dz = __fsub_rn(rz, kps[k * 3 + 2]);
            float sq = __fadd_rn(__fadd_rn(__fmul_rn(dx, dx), __fmul_rn(dy, dy)),
                                 __fmul_rn(dz, dz));
            if (sq < best) { best = sq; nn = k; }   // strict < == np.argmin
        }
        float w = fmaxf(__fsub_rn(1.0f, __fdiv_rn(__fsqrt_rn(best), KPE)), 0.0f);
        const int r = t >> 4, n = t & 15;
        wv[r * 17 + n] = w; nnv[r * 17 + n] = nn;
        __syncthreads();
        const int mm = t >> 4, cl = t & 15;
        float sacc = 0.f;
#pragma unroll
        for (int n2 = 0; n2 < 16; ++n2)
            sacc += (nnv[cl * 17 + n2] == mm) ? wv[cl * 17 + n2] : 0.f;
        s_g[mm * 8192 + b * 16 + cl] = sacc;
    } else if (b < 528) {
        // ---- W transpose+convert, one m per block ----
        const int m = b - 512;
        __shared__ float tile[64 * 129];
#pragma unroll
        for (int j = 0; j < 32; ++j) {
            int idx = j * 256 + t;             // i = idx>>7, n = idx&127
            tile[(idx >> 7) * 129 + (idx & 127)] = Wf[m * 8192 + idx];
        }
        __syncthreads();
#pragma unroll
        for (int j = 0; j < 32; ++j) {
            int idx = j * 256 + t;             // n = idx>>6, i = idx&63
            Wb[m * 8192 + idx] = f2bf(tile[(idx & 63) * 129 + (idx >> 6)]);
        }
    } else if (b < 1040) {
        // ---- x -> bf16 ----
        const int base = (b - 528) * 1024;
#pragma unroll
        for (int j = 0; j < 4; ++j) {
            int idx4 = base + j * 256 + t;
            const float4 v = reinterpret_cast<const float4*>(x)[idx4];
            ushort4 o;
            o.x = f2bf(v.x); o.y = f2bf(v.y); o.z = f2bf(v.z); o.w = f2bf(v.w);
            reinterpret_cast<ushort4*>(xb)[idx4] = o;
        }
    } else {
        // ---- zero out ----
        const int base = (b - 1040) * 1024;
        const float4 z = {0.f, 0.f, 0.f, 0.f};
#pragma unroll
        for (int j = 0; j < 4; ++j)
            reinterpret_cast<float4*>(out)[base + j * 256 + t] = z;
    }
}

__global__ __launch_bounds__(256) void kmain(
    const unsigned short* __restrict__ xb, const int* __restrict__ esrc,
    const unsigned short* __restrict__ Wb, const float* __restrict__ s_g,
    float* __restrict__ out)
{
    const uint4* xb4 = reinterpret_cast<const uint4*>(xb);   // 8 uint4 / row
    const uint4* wb4 = reinterpret_cast<const uint4*>(Wb);   // 1024 uint4 / m
    const int t    = threadIdx.x;
    const int w    = t >> 6, lane = t & 63;
    const int l16  = lane & 15, quad = lane >> 4;
    const int rt   = blockIdx.x >> 1, ks = blockIdx.x & 1;
    const int r0   = rt * 16;
    const int m0   = ks * 8;
    const int bc0  = (w * 32 + l16) * 8 + quad;       // B frag base, col half 0
    const int bc1  = (w * 32 + 16 + l16) * 8 + quad;  // col half 1
    const int srcbase = (r0 + l16) * 16 + m0;
    const int svbase  = r0 + quad * 4;

    // all 8 src indices up front — one fully parallel gather round
    int srcv[8];
#pragma unroll
    for (int i = 0; i < 8; ++i) srcv[i] = esrc[srcbase + i];

    uint4  A[3][2];            // 2-ahead ring
    uint4  B[2][4];            // 1-ahead
    float4 SV[2];

    A[0][0] = xb4[srcv[0] * 8 + quad];  A[0][1] = xb4[srcv[0] * 8 + 4 + quad];
    A[1][0] = xb4[srcv[1] * 8 + quad];  A[1][1] = xb4[srcv[1] * 8 + 4 + quad];
    B[0][0] = wb4[m0 * 1024 + bc0];     B[0][1] = wb4[m0 * 1024 + bc0 + 4];
    B[0][2] = wb4[m0 * 1024 + bc1];     B[0][3] = wb4[m0 * 1024 + bc1 + 4];
    SV[0]   = *reinterpret_cast<const float4*>(&s_g[m0 * 8192 + svbase]);

    floatx4 acc0 = {0.f, 0.f, 0.f, 0.f};
    floatx4 acc1 = {0.f, 0.f, 0.f, 0.f};
    const floatx4 zed = {0.f, 0.f, 0.f, 0.f};

#pragma unroll
    for (int i = 0; i < 8; ++i) {
        if (i + 2 < 8) {       // A 2-ahead
            const int s2 = srcv[i + 2];
            A[(i + 2) % 3][0] = xb4[s2 * 8 + quad];
            A[(i + 2) % 3][1] = xb4[s2 * 8 + 4 + quad];
        }
        if (i + 1 < 8) {       // B/SV 1-ahead
            const int mb = (m0 + i + 1) * 1024;
            B[(i + 1) & 1][0] = wb4[mb + bc0];
            B[(i + 1) & 1][1] = wb4[mb + bc0 + 4];
            B[(i + 1) & 1][2] = wb4[mb + bc1];
            B[(i + 1) & 1][3] = wb4[mb + bc1 + 4];
            SV[(i + 1) & 1] = *reinterpret_cast<const float4*>(
                &s_g[(m0 + i + 1) * 8192 + svbase]);
        }
        const short8 a0 = __builtin_bit_cast(short8, A[i % 3][0]);
        const short8 a1 = __builtin_bit_cast(short8, A[i % 3][1]);
        floatx4 t0 = __builtin_amdgcn_mfma_f32_16x16x32_bf16(
            a0, __builtin_bit_cast(short8, B[i & 1][0]), zed, 0, 0, 0);
        t0 = __builtin_amdgcn_mfma_f32_16x16x32_bf16(
            a1, __builtin_bit_cast(short8, B[i & 1][1]), t0, 0, 0, 0);
        floatx4 t1 = __builtin_amdgcn_mfma_f32_16x16x32_bf16(
            a0, __builtin_bit_cast(short8, B[i & 1][2]), zed, 0, 0, 0);
        t1 = __builtin_amdgcn_mfma_f32_16x16x32_bf16(
            a1, __builtin_bit_cast(short8, B[i & 1][3]), t1, 0, 0, 0);
        const float4 sv = SV[i & 1];
#pragma unroll
        for (int v = 0; v < 4; ++v) {
            const float s4 = (v == 0) ? sv.x : (v == 1) ? sv.y
                           : (v == 2) ? sv.z : sv.w;
            acc0[v] += s4 * t0[v];
            acc1[v] += s4 * t1[v];
        }
    }

    // ---- epilogue: C/D layout col=lane&15, row=quad*4+reg; k-split add ----
    const int col0 = w * 32 + l16;
    const int rowb = r0 + quad * 4;
#pragma unroll
    for (int v = 0; v < 4; ++v) {
        atomicAdd(&out[(rowb + v) * 128 + col0],      acc0[v]);
        atomicAdd(&out[(rowb + v) * 128 + col0 + 16], acc1[v]);
    }
}

extern "C" void kernel_launch(void* const* d_in, const int* in_sizes, int n_in,
                              void* d_out, int out_size, void* d_ws, size_t ws_size,
                              hipStream_t stream) {
    const float* x    = (const float*)d_in[0];
    const float* pos  = (const float*)d_in[1];
    const int*   esrc = (const int*)d_in[2];
    const int*   etgt = (const int*)d_in[3];
    const float* kpts = (const float*)d_in[4];
    const float* Wf   = (const float*)d_in[5];
    float* out = (float*)d_out;

    char* wsb = (char*)d_ws;
    unsigned short* Wb = (unsigned short*)wsb;                // 256 KiB
    unsigned short* xb = (unsigned short*)(wsb + 262144);     // 4 MiB
    float*          sg = (float*)(wsb + 262144 + 4194304);    // 512 KiB

    hipLaunchKernelGGL(kprep, dim3(1296), dim3(256), 0, stream,
                       Wf, x, pos, esrc, etgt, kpts, Wb, xb, sg, out);
    hipLaunchKernelGGL(kmain, dim3(1024), dim3(256), 0, stream,
                       xb, esrc, Wb, sg, out);
}